// Round 4
// baseline (719.876 us; speedup 1.0000x reference)
//
#include <hip/hip_runtime.h>

#define HIDDEN 5120
#define NEXP 160
#define NGRP 8
#define GSIZE 20
#define TOPKG 3
#define TOPK 6

#define KC 32     // k-chunk staged in LDS
#define EPW 20    // experts per wave; 4 waves = 80 experts = one half
#define TTILE 128 // tokens per gemm block (2 per lane)

// ---------- K0: transpose W [160][5120] -> wT [5120][160], LDS-tiled ----------
// both global sides coalesced; LDS stride 161 -> conflict-free both phases
__global__ __launch_bounds__(256) void transpose_w(const float* __restrict__ w,
                                                   float* __restrict__ wT) {
    __shared__ float buf[64][161];
    const int tid = threadIdx.x;
    const int k0  = blockIdx.x * 64;
#pragma unroll
    for (int it = 0; it < 40; ++it) {            // 160 e-rows x 64 k
        int idx = it * 256 + tid;
        int e = idx >> 6;
        int k = idx & 63;
        buf[k][e] = w[(size_t)e * HIDDEN + k0 + k];
    }
    __syncthreads();
#pragma unroll
    for (int it = 0; it < 40; ++it) {            // 64 k-rows x 160 e
        int idx = it * 256 + tid;
        int k = idx / 160;
        int e = idx - k * 160;
        wT[(size_t)(k0 + k) * NEXP + e] = buf[k][e];
    }
}

// ---------- K1: partial logits via scalar-broadcast FMA, 2 tokens/lane ----------
// lane owns tokens (t0+lane) and (t0+64+lane): 40 FMAs per 80B wave-uniform s_load.
// grid = (T/128) tiles x 2 expert-halves x KS k-splits; KS=4 -> 1024 blocks ->
// 4 blocks/CU x 4 waves = 16 waves/CU.
template <int KS>
__global__ __launch_bounds__(256, 4) void gemm_logits(const float* __restrict__ x,
                                                      const float* __restrict__ wT,
                                                      float* __restrict__ part, int T) {
    constexpr int KPART = HIDDEN / KS;
    constexpr int NCH   = KPART / KC;

    __shared__ float xs[KC][TTILE];   // transposed tile: conflict-free reads & writes

    const int tid  = threadIdx.x;
    const int lane = tid & 63;
    const int wv   = tid >> 6;                        // 0..3
    const int bx   = blockIdx.x;
    const int tile = bx / (2 * KS);
    const int rem  = bx - tile * (2 * KS);
    const int half = rem / KS;
    const int ks   = rem - half * KS;
    const int t0   = tile * TTILE;
    const int e0   = __builtin_amdgcn_readfirstlane(half * 80 + wv * EPW);

    // staging: thread (lane, wv) owns k-cols wv*4+{0..3,16..19} of rows lane, lane+64
    const float* xA = x + (size_t)(t0 + lane) * HIDDEN + ks * KPART + wv * 4;
    const float* xB = xA + (size_t)64 * HIDDEN;

    float4 va0 = *(const float4*)(xA);
    float4 vb0 = *(const float4*)(xA + 16);
    float4 va1 = *(const float4*)(xB);
    float4 vb1 = *(const float4*)(xB + 16);

    float accA[EPW], accB[EPW];
#pragma unroll
    for (int j = 0; j < EPW; ++j) { accA[j] = 0.f; accB[j] = 0.f; }

    const float* wbase = wT + (size_t)ks * KPART * NEXP + e0;

    for (int c = 0; c < NCH; ++c) {
        __syncthreads();
        const int kw = wv * 4;
        xs[kw + 0][lane] = va0.x;  xs[kw + 1][lane] = va0.y;
        xs[kw + 2][lane] = va0.z;  xs[kw + 3][lane] = va0.w;
        xs[kw + 16][lane] = vb0.x; xs[kw + 17][lane] = vb0.y;
        xs[kw + 18][lane] = vb0.z; xs[kw + 19][lane] = vb0.w;
        xs[kw + 0][lane + 64] = va1.x;  xs[kw + 1][lane + 64] = va1.y;
        xs[kw + 2][lane + 64] = va1.z;  xs[kw + 3][lane + 64] = va1.w;
        xs[kw + 16][lane + 64] = vb1.x; xs[kw + 17][lane + 64] = vb1.y;
        xs[kw + 18][lane + 64] = vb1.z; xs[kw + 19][lane + 64] = vb1.w;
        __syncthreads();

        int cn = (c + 1 < NCH) ? c + 1 : c;           // prefetch next chunk
        va0 = *(const float4*)(xA + (size_t)cn * KC);
        vb0 = *(const float4*)(xA + (size_t)cn * KC + 16);
        va1 = *(const float4*)(xB + (size_t)cn * KC);
        vb1 = *(const float4*)(xB + (size_t)cn * KC + 16);

        const float* wp = wbase + (size_t)c * KC * NEXP;   // wave-uniform

        float caccA[EPW], caccB[EPW];                      // 2-level sum (precision)
#pragma unroll
        for (int j = 0; j < EPW; ++j) { caccA[j] = 0.f; caccB[j] = 0.f; }

#pragma unroll
        for (int kk = 0; kk < KC; ++kk) {
            float xa = xs[kk][lane];                       // ds_read2_b32 pair
            float xb = xs[kk][lane + 64];
            const float* wr = wp + kk * NEXP;              // -> s_load x16 + x4
#pragma unroll
            for (int j = 0; j < EPW; ++j) {
                caccA[j] = fmaf(xa, wr[j], caccA[j]);
                caccB[j] = fmaf(xb, wr[j], caccB[j]);
            }
        }
#pragma unroll
        for (int j = 0; j < EPW; ++j) { accA[j] += caccA[j]; accB[j] += caccB[j]; }
    }

    float* lpA = part + (size_t)ks * T * NEXP + (size_t)(t0 + lane) * NEXP + e0;
    float* lpB = lpA + (size_t)64 * NEXP;
#pragma unroll
    for (int j = 0; j < EPW; j += 4) {
        *(float4*)(lpA + j) = make_float4(accA[j], accA[j+1], accA[j+2], accA[j+3]);
        *(float4*)(lpB + j) = make_float4(accB[j], accB[j+1], accB[j+2], accB[j+3]);
    }
}

// ---------- K2: combine K-partials + grouped top-k, 4 threads/token ----------
#define TM 64      // tokens per K2 block
#define ROWP 165   // odd stride spreads scan reads across banks

template <int KS>
__global__ __launch_bounds__(256, 2) void moe_topk(const float* __restrict__ part,
                                                   float* __restrict__ out, int T) {
    __shared__ float rows[TM][ROWP];
    __shared__ float gmaxs[TM][NGRP];
    __shared__ float candV[TM][4][TOPK];
    __shared__ int   candI[TM][4][TOPK];

    const int tid = threadIdx.x;
    const int t0  = blockIdx.x * TM;

    // stage 64 rows (deterministic sum of the KS partials), coalesced
#pragma unroll
    for (int i = 0; i < 10; ++i) {
        int f4 = tid + 256 * i;          // 2560 float4s = 64 tokens x 40
        int t  = f4 / 40;
        int c4 = f4 - t * 40;
        const float4* p0 = (const float4*)(part + (size_t)t0 * NEXP);
        float4 s = p0[f4];
#pragma unroll
        for (int ks = 1; ks < KS; ++ks) {
            const float4* pk = (const float4*)(part + (size_t)ks * T * NEXP + (size_t)t0 * NEXP);
            float4 a = pk[f4];
            s.x += a.x; s.y += a.y; s.z += a.z; s.w += a.w;
        }
        float* dst = &rows[t][c4 * 4];
        dst[0] = s.x; dst[1] = s.y; dst[2] = s.z; dst[3] = s.w;
    }
    __syncthreads();

    const int tl  = tid >> 2;            // token within block
    const int sub = tid & 3;             // 4 threads/token; sub owns groups 2s,2s+1
    const float* row = rows[tl];

    // phase A: group maxes
#pragma unroll
    for (int gg = 0; gg < 2; ++gg) {
        int g = sub * 2 + gg;
        float m = -3e38f;
#pragma unroll
        for (int j = 0; j < GSIZE; ++j) m = fmaxf(m, row[g * GSIZE + j]);
        gmaxs[tl][g] = m;
    }
    __syncthreads();

    // top-3 groups, replicated per thread (lowest g wins ties, matches lax.top_k)
    float gm[NGRP];
#pragma unroll
    for (int g = 0; g < NGRP; ++g) gm[g] = gmaxs[tl][g];
    unsigned gmask = 0;
#pragma unroll
    for (int r = 0; r < TOPKG; ++r) {
        float bv = -3e38f; int bi = 0;
#pragma unroll
        for (int g = 0; g < NGRP; ++g) {
            bool elig = !((gmask >> g) & 1);
            if (elig && gm[g] > bv) { bv = gm[g]; bi = g; }
        }
        gmask |= 1u << bi;
    }

    // phase B: local top-6 of my (selected) groups via stable insertion sort
    float lv[TOPK]; int li[TOPK];
#pragma unroll
    for (int r = 0; r < TOPK; ++r) { lv[r] = -3e38f; li[r] = 1 << 20; }
#pragma unroll
    for (int gg = 0; gg < 2; ++gg) {
        int g = sub * 2 + gg;
        if (!((gmask >> g) & 1)) continue;
#pragma unroll
        for (int j = 0; j < GSIZE; ++j) {
            int e = g * GSIZE + j;
            float v = row[e];
            if (v > lv[TOPK - 1]) {
                lv[TOPK - 1] = v; li[TOPK - 1] = e;
#pragma unroll
                for (int q = TOPK - 1; q > 0; --q) {
                    if (lv[q] > lv[q - 1]) {
                        float tv = lv[q]; lv[q] = lv[q - 1]; lv[q - 1] = tv;
                        int   ti = li[q]; li[q] = li[q - 1]; li[q - 1] = ti;
                    }
                }
            }
        }
    }
#pragma unroll
    for (int r = 0; r < TOPK; ++r) {
        candV[tl][sub][r] = lv[r];
        candI[tl][sub][r] = li[r];
    }
    __syncthreads();

    // merge: registers only, compile-time indices.
    // selection by lexicographic (value desc, index asc) with (pv,pi) exclusion.
    if (sub == 0) {
        float cv[4][TOPK]; int ci[4][TOPK];
#pragma unroll
        for (int s = 0; s < 4; ++s)
#pragma unroll
            for (int q = 0; q < TOPK; ++q) { cv[s][q] = candV[tl][s][q]; ci[s][q] = candI[tl][s][q]; }

        float vals[TOPK]; int idxs[TOPK];
        float pv = 3e38f; int pi = -1;
#pragma unroll
        for (int r = 0; r < TOPK; ++r) {
            float bv = -3e38f; int bi = 1 << 20;
#pragma unroll
            for (int s = 0; s < 4; ++s) {
#pragma unroll
                for (int q = 0; q < TOPK; ++q) {
                    float v = cv[s][q]; int e = ci[s][q];
                    bool elig = (v < pv) || (v == pv && e > pi);
                    bool better = (v > bv) || (v == bv && e < bi);
                    if (elig && better) { bv = v; bi = e; }
                }
            }
            vals[r] = bv; idxs[r] = bi; pv = bv; pi = bi;
        }

        float m = vals[0];               // global max (its group is always selected)
        float ssum = 0.f, wv6[TOPK];
#pragma unroll
        for (int r = 0; r < TOPK; ++r) { wv6[r] = expf(vals[r] - m); ssum += wv6[r]; }
        float inv = 1.f / (ssum + 1e-20f);

        int t = t0 + tl;
#pragma unroll
        for (int r = 0; r < TOPK; ++r) {
            out[(size_t)t * TOPK + r] = (float)idxs[r];
            out[(size_t)T * TOPK + (size_t)t * TOPK + r] = wv6[r] * inv;
        }
    }
}

extern "C" void kernel_launch(void* const* d_in, const int* in_sizes, int n_in,
                              void* d_out, int out_size, void* d_ws, size_t ws_size,
                              hipStream_t stream) {
    const float* x = (const float*)d_in[0];
    const float* w = (const float*)d_in[1];
    float* out = (float*)d_out;
    const int T = in_sizes[0] / HIDDEN;                  // 16384

    float* wT   = (float*)d_ws;                          // 5120*160 floats (3.1 MB)
    float* part = wT + (size_t)HIDDEN * NEXP;

    transpose_w<<<HIDDEN / 64, 256, 0, stream>>>(w, wT);

    size_t need4 = ((size_t)HIDDEN * NEXP + (size_t)4 * T * NEXP) * sizeof(float);
    if (ws_size >= need4) {
        gemm_logits<4><<<(T / TTILE) * 2 * 4, 256, 0, stream>>>(x, wT, part, T);
        moe_topk<4><<<T / TM, 256, 0, stream>>>(part, out, T);
    } else {
        gemm_logits<2><<<(T / TTILE) * 2 * 2, 256, 0, stream>>>(x, wT, part, T);
        moe_topk<2><<<T / TM, 256, 0, stream>>>(part, out, T);
    }
}